// Round 1
// baseline (499.248 us; speedup 1.0000x reference)
//
#include <hip/hip_runtime.h>
#include <cstdio>
#include <cstdint>

// GridSelfAttention: N=320 seq, C=128 ch, H=4 heads, D=32 head-dim.
// k0 prep -> k1 LN+proj GEMM -> k2 attention -> k3 output GEMM.

#define NSEQ 320
#define CCH  128
#define NN   102400        // NSEQ*NSEQ
#define QK_SCALE 0.17677669529663687f   // 1/sqrt(32), folded into Wq
#define LN_EPS 1e-5f
#define NEG_BIG -1e9f

typedef __bf16 bf16x8 __attribute__((ext_vector_type(8)));
typedef float  f32x4  __attribute__((ext_vector_type(4)));

__device__ __forceinline__ unsigned short f2bf(float f) {
    unsigned int u = __float_as_uint(f);
    unsigned int r = (u + 0x7FFFu + ((u >> 16) & 1u)) >> 16;  // RNE
    return (unsigned short)r;
}
__device__ __forceinline__ float bf2f(unsigned short h) {
    return __uint_as_float(((unsigned int)h) << 16);
}

// ---------------- k0: weight prep ----------------
// WcatT[n][c] (bf16, row-major [576][128]): n<128 q(*scale) | k | v | gate | 512..515 pair-bias | pad 0
// woutb: bf16 copy of w_out [128][128] (already Bt layout: row=out, col=in)
// maskT[b][k] = pair_mask[k][b]
__global__ __launch_bounds__(256) void prep_kernel(
    const float* __restrict__ wq, const float* __restrict__ wk, const float* __restrict__ wv,
    const float* __restrict__ wg, const float* __restrict__ wpb, const float* __restrict__ wo,
    const int* __restrict__ pmask,
    unsigned short* __restrict__ wcat, unsigned short* __restrict__ woutb, int* __restrict__ maskT)
{
    int idx = blockIdx.x * 256 + threadIdx.x;
    if (idx < 576 * 128) {
        int n = idx >> 7, c = idx & 127;
        float v;
        if      (n < 128) v = wq[c * 128 + n] * QK_SCALE;
        else if (n < 256) v = wk[c * 128 + (n - 128)];
        else if (n < 384) v = wv[c * 128 + (n - 256)];
        else if (n < 512) v = wg[c * 128 + (n - 384)];
        else if (n < 516) v = wpb[c * 4 + (n - 512)];
        else              v = 0.f;
        wcat[idx] = f2bf(v);
    } else if (idx < 576 * 128 + 128 * 128) {
        int i = idx - 576 * 128;
        woutb[i] = f2bf(wo[i]);
    } else if (idx < 576 * 128 + 128 * 128 + NN) {
        int i = idx - (576 * 128 + 128 * 128);
        int b = i / NSEQ, k = i - b * NSEQ;
        maskT[i] = pmask[k * NSEQ + b];
    }
}

// ---------------- k1: LayerNorm + fused projection GEMM ----------------
// Per block: 64 rows. A = LN(act) tile bf16 [64][128] (pad 136), B = WcatT 64-col chunks.
// Epilogue scatters to q/k/v (bf16), gate (sigmoid, bf16), biasH (fp32 [H][N][N]).
__global__ __launch_bounds__(256, 4) void ln_proj_kernel(
    const float* __restrict__ act, const float* __restrict__ gamma, const float* __restrict__ beta,
    const unsigned short* __restrict__ wcat,
    unsigned short* __restrict__ qb, unsigned short* __restrict__ kb, unsigned short* __restrict__ vb,
    unsigned short* __restrict__ gb, float* __restrict__ biasH)
{
    __shared__ __align__(16) float          fs[64 * 132];            // fp32 act stage, later aliased by B
    __shared__ __align__(16) unsigned short A_lds[64 * 136];
    unsigned short* B_lds = (unsigned short*)fs;                     // alias (33792 B >= 17408 B)

    const int tid  = threadIdx.x;
    const int row0 = blockIdx.x * 64;

    // stage act tile (contiguous 64x128 fp32), coalesced float4
    const float4* actv = (const float4*)(act + (size_t)row0 * 128);
    #pragma unroll
    for (int it = 0; it < 8; ++it) {
        int f = it * 256 + tid;
        int row = f >> 5, c4 = f & 31;
        float4 v = actv[f];
        *(float4*)&fs[row * 132 + c4 * 4] = v;
    }
    __syncthreads();

    // LayerNorm: 4 threads per row
    {
        int row = tid >> 2, seg = tid & 3;
        const float* rp = &fs[row * 132 + seg * 32];
        float vals[32];
        float s = 0.f, sq = 0.f;
        #pragma unroll
        for (int i = 0; i < 32; ++i) { float v = rp[i]; vals[i] = v; s += v; sq += v * v; }
        s  += __shfl_xor(s, 1);  sq += __shfl_xor(sq, 1);
        s  += __shfl_xor(s, 2);  sq += __shfl_xor(sq, 2);
        float mean = s * (1.f / 128.f);
        float var  = sq * (1.f / 128.f) - mean * mean;
        float rstd = rsqrtf(var + LN_EPS);
        #pragma unroll
        for (int j = 0; j < 4; ++j) {
            int c0 = seg * 32 + j * 8;
            float4 g0 = *(const float4*)&gamma[c0];
            float4 g1 = *(const float4*)&gamma[c0 + 4];
            float4 b0 = *(const float4*)&beta[c0];
            float4 b1 = *(const float4*)&beta[c0 + 4];
            union { uint4 u; unsigned short us[8]; } pk;
            pk.us[0] = f2bf((vals[j*8+0] - mean) * rstd * g0.x + b0.x);
            pk.us[1] = f2bf((vals[j*8+1] - mean) * rstd * g0.y + b0.y);
            pk.us[2] = f2bf((vals[j*8+2] - mean) * rstd * g0.z + b0.z);
            pk.us[3] = f2bf((vals[j*8+3] - mean) * rstd * g0.w + b0.w);
            pk.us[4] = f2bf((vals[j*8+4] - mean) * rstd * g1.x + b1.x);
            pk.us[5] = f2bf((vals[j*8+5] - mean) * rstd * g1.y + b1.y);
            pk.us[6] = f2bf((vals[j*8+6] - mean) * rstd * g1.z + b1.z);
            pk.us[7] = f2bf((vals[j*8+7] - mean) * rstd * g1.w + b1.w);
            *(uint4*)&A_lds[row * 136 + c0] = pk.u;
        }
    }
    __syncthreads();

    const int wave = tid >> 6, lane = tid & 63, l15 = lane & 15, l4 = lane >> 4;
    bf16x8 afrag[4];
    #pragma unroll
    for (int kc = 0; kc < 4; ++kc)
        afrag[kc] = *(const bf16x8*)&A_lds[(wave * 16 + l15) * 136 + kc * 32 + l4 * 8];

    for (int nt = 0; nt < 9; ++nt) {
        // stage B chunk [64 n][128 k] bf16 (pad 136)
        #pragma unroll
        for (int it = 0; it < 4; ++it) {
            int f = it * 256 + tid;
            int row = f >> 4, c16 = f & 15;
            uint4 u = *(const uint4*)&wcat[(nt * 64 + row) * 128 + c16 * 8];
            *(uint4*)&B_lds[row * 136 + c16 * 8] = u;
        }
        __syncthreads();
        f32x4 acc[4];
        #pragma unroll
        for (int ns = 0; ns < 4; ++ns) { f32x4 z = {0.f,0.f,0.f,0.f}; acc[ns] = z; }
        #pragma unroll
        for (int ns = 0; ns < 4; ++ns)
            #pragma unroll
            for (int kc = 0; kc < 4; ++kc) {
                bf16x8 bfrag = *(const bf16x8*)&B_lds[(ns * 16 + l15) * 136 + kc * 32 + l4 * 8];
                acc[ns] = __builtin_amdgcn_mfma_f32_16x16x32_bf16(afrag[kc], bfrag, acc[ns], 0, 0, 0);
            }
        // epilogue scatter
        #pragma unroll
        for (int ns = 0; ns < 4; ++ns) {
            int j = nt * 64 + ns * 16 + l15;
            #pragma unroll
            for (int reg = 0; reg < 4; ++reg) {
                int r = row0 + wave * 16 + l4 * 4 + reg;
                float v = acc[ns][reg];
                if      (j < 128) qb[(size_t)r * 128 + j]         = f2bf(v);
                else if (j < 256) kb[(size_t)r * 128 + (j - 128)] = f2bf(v);
                else if (j < 384) vb[(size_t)r * 128 + (j - 256)] = f2bf(v);
                else if (j < 512) gb[(size_t)r * 128 + (j - 384)] = f2bf(1.f / (1.f + __expf(-v)));
                else if (j < 516) biasH[(size_t)(j - 512) * NN + r] = v;
            }
        }
        __syncthreads();
    }
}

// ---------------- k2: attention ----------------
// block = (b, h, q-tile of 64). 4 waves x 16 q-rows. Q/K frags direct from global.
// V transposed via LDS once. P->LDS per-wave for PV A-operand. Gate fused in epilogue.
__global__ __launch_bounds__(256, 2) void attn_kernel(
    const unsigned short* __restrict__ qb, const unsigned short* __restrict__ kb,
    const unsigned short* __restrict__ vb, const unsigned short* __restrict__ gb,
    const float* __restrict__ biasH, const int* __restrict__ maskT,
    unsigned short* __restrict__ waG)
{
    __shared__ __align__(16) unsigned short Vt[32 * 336];       // V^T [d][key], stride 336
    __shared__ __align__(16) unsigned short Wl[4 * 16 * 328];   // per-wave P [q][key], stride 328

    const int tid  = threadIdx.x;
    const int bid  = blockIdx.x;
    const int b    = bid / 20;
    const int h    = (bid / 5) & 3;
    const int qblk = bid % 5;
    const int wave = tid >> 6, lane = tid & 63, l15 = lane & 15, l4 = lane >> 4;

    // stage V^T: [320 keys x 32 d] -> [32][320]
    #pragma unroll
    for (int it = 0; it < 5; ++it) {
        int idx = it * 256 + tid;
        int key = idx >> 2, part = idx & 3;
        union { uint4 u; unsigned short us[8]; } v;
        v.u = *(const uint4*)&vb[(size_t)(b * NSEQ + key) * 128 + h * 32 + part * 8];
        #pragma unroll
        for (int i = 0; i < 8; ++i)
            Vt[(part * 8 + i) * 336 + key] = v.us[i];
    }
    __syncthreads();

    const int qrow = qblk * 64 + wave * 16;   // q base of this wave (0..319)

    // A-frag: Q rows, directly in MFMA A layout from global
    bf16x8 aQ = *(const bf16x8*)&qb[(size_t)(b * NSEQ + qrow + l15) * 128 + h * 32 + l4 * 8];

    // S = Q K^T : 20 key-tiles of 16, K=32 in one MFMA each. B-frag direct from global.
    f32x4 s[20];
    #pragma unroll
    for (int t = 0; t < 20; ++t) {
        bf16x8 bK = *(const bf16x8*)&kb[(size_t)(b * NSEQ + t * 16 + l15) * 128 + h * 32 + l4 * 8];
        f32x4 z = {0.f, 0.f, 0.f, 0.f};
        s[t] = __builtin_amdgcn_mfma_f32_16x16x32_bf16(aQ, bK, z, 0, 0, 0);
    }

    // + bias[h][q][key] (fp32, L2-resident, coalesced), mask (key,b) -> -1e9
    const float* bp = biasH + (size_t)h * NN + (size_t)(qrow + l4 * 4) * NSEQ + l15;
    const int*   mp = maskT + b * NSEQ + l15;
    #pragma unroll
    for (int t = 0; t < 20; ++t) {
        int m = mp[t * 16];
        f32x4 sv = s[t];
        #pragma unroll
        for (int reg = 0; reg < 4; ++reg)
            sv[reg] = m ? (sv[reg] + bp[reg * NSEQ + t * 16]) : NEG_BIG;
        s[t] = sv;
    }

    // softmax over keys per q-row (reg): local over 20 tiles + shfl_xor over 16 lanes
    #pragma unroll
    for (int reg = 0; reg < 4; ++reg) {
        float mx = -3.4e38f;
        #pragma unroll
        for (int t = 0; t < 20; ++t) mx = fmaxf(mx, s[t][reg]);
        mx = fmaxf(mx, __shfl_xor(mx, 1));
        mx = fmaxf(mx, __shfl_xor(mx, 2));
        mx = fmaxf(mx, __shfl_xor(mx, 4));
        mx = fmaxf(mx, __shfl_xor(mx, 8));
        float l = 0.f;
        #pragma unroll
        for (int t = 0; t < 20; ++t) { float p = __expf(s[t][reg] - mx); s[t][reg] = p; l += p; }
        l += __shfl_xor(l, 1); l += __shfl_xor(l, 2); l += __shfl_xor(l, 4); l += __shfl_xor(l, 8);
        float wv = 1.f / l;   // all-masked row: l = 320 -> uniform 1/320, matches reference
        #pragma unroll
        for (int t = 0; t < 20; ++t) s[t][reg] *= wv;
    }

    // P -> LDS (own wave's region; same-wave RAW, compiler inserts lgkmcnt)
    unsigned short* wl = &Wl[wave * 16 * 328];
    #pragma unroll
    for (int t = 0; t < 20; ++t)
        #pragma unroll
        for (int reg = 0; reg < 4; ++reg)
            wl[(l4 * 4 + reg) * 328 + t * 16 + l15] = f2bf(s[t][reg]);

    // PV: wa[16 q][32 d], K=320 in 10 chunks of 32
    f32x4 acc[2];
    { f32x4 z = {0.f,0.f,0.f,0.f}; acc[0] = z; acc[1] = z; }
    #pragma unroll
    for (int kc = 0; kc < 10; ++kc) {
        bf16x8 aW = *(const bf16x8*)&wl[l15 * 328 + kc * 32 + l4 * 8];
        #pragma unroll
        for (int ns = 0; ns < 2; ++ns) {
            bf16x8 bV = *(const bf16x8*)&Vt[(ns * 16 + l15) * 336 + kc * 32 + l4 * 8];
            acc[ns] = __builtin_amdgcn_mfma_f32_16x16x32_bf16(aW, bV, acc[ns], 0, 0, 0);
        }
    }

    // epilogue: wa * gate -> bf16
    #pragma unroll
    for (int ns = 0; ns < 2; ++ns)
        #pragma unroll
        for (int reg = 0; reg < 4; ++reg) {
            int r   = b * NSEQ + qrow + l4 * 4 + reg;
            int col = h * 32 + ns * 16 + l15;
            float g = bf2f(gb[(size_t)r * 128 + col]);
            waG[(size_t)r * 128 + col] = f2bf(acc[ns][reg] * g);
        }
}

// ---------------- k3: output projection ----------------
// out[64 rows][128] = (wa*gate) @ w_out^T ; B = woutb rows (already Bt layout)
__global__ __launch_bounds__(256, 4) void out_proj_kernel(
    const unsigned short* __restrict__ waG, const unsigned short* __restrict__ woutb,
    float* __restrict__ out)
{
    __shared__ __align__(16) unsigned short A_lds[64 * 136];
    __shared__ __align__(16) unsigned short B_lds[128 * 136];
    const int tid  = threadIdx.x;
    const int row0 = blockIdx.x * 64;

    #pragma unroll
    for (int it = 0; it < 4; ++it) {
        int f = it * 256 + tid;
        int row = f >> 4, c16 = f & 15;
        uint4 u = *(const uint4*)&waG[(size_t)(row0 + row) * 128 + c16 * 8];
        *(uint4*)&A_lds[row * 136 + c16 * 8] = u;
    }
    #pragma unroll
    for (int it = 0; it < 8; ++it) {
        int f = it * 256 + tid;
        int row = f >> 4, c16 = f & 15;
        uint4 u = *(const uint4*)&woutb[f * 8];
        *(uint4*)&B_lds[row * 136 + c16 * 8] = u;
    }
    __syncthreads();

    const int wave = tid >> 6, lane = tid & 63, l15 = lane & 15, l4 = lane >> 4;
    bf16x8 afrag[4];
    #pragma unroll
    for (int kc = 0; kc < 4; ++kc)
        afrag[kc] = *(const bf16x8*)&A_lds[(wave * 16 + l15) * 136 + kc * 32 + l4 * 8];
    f32x4 acc[8];
    #pragma unroll
    for (int ns = 0; ns < 8; ++ns) { f32x4 z = {0.f,0.f,0.f,0.f}; acc[ns] = z; }
    #pragma unroll
    for (int ns = 0; ns < 8; ++ns)
        #pragma unroll
        for (int kc = 0; kc < 4; ++kc) {
            bf16x8 bfrag = *(const bf16x8*)&B_lds[(ns * 16 + l15) * 136 + kc * 32 + l4 * 8];
            acc[ns] = __builtin_amdgcn_mfma_f32_16x16x32_bf16(afrag[kc], bfrag, acc[ns], 0, 0, 0);
        }
    #pragma unroll
    for (int ns = 0; ns < 8; ++ns)
        #pragma unroll
        for (int reg = 0; reg < 4; ++reg) {
            int r = row0 + wave * 16 + l4 * 4 + reg;
            out[(size_t)r * 128 + ns * 16 + l15] = acc[ns][reg];
        }
}

// ---------------- launch ----------------
extern "C" void kernel_launch(void* const* d_in, const int* in_sizes, int n_in,
                              void* d_out, int out_size, void* d_ws, size_t ws_size,
                              hipStream_t stream)
{
    (void)in_sizes; (void)n_in; (void)out_size;
    const float* act  = (const float*)d_in[0];
    const int*   pmsk = (const int*)d_in[1];
    const float* gam  = (const float*)d_in[2];
    const float* bet  = (const float*)d_in[3];
    const float* wpb  = (const float*)d_in[4];
    const float* wq   = (const float*)d_in[5];
    const float* wk   = (const float*)d_in[6];
    const float* wv   = (const float*)d_in[7];
    const float* wg   = (const float*)d_in[8];
    const float* wo   = (const float*)d_in[9];
    float* out = (float*)d_out;

    char* ws = (char*)d_ws;
    unsigned short* wcat  = (unsigned short*)(ws + 0);          //   147456 B
    unsigned short* woutb = (unsigned short*)(ws + 147456);     //    32768 B
    int*            maskT = (int*)           (ws + 180224);     //   409600 B
    float*          biasH = (float*)         (ws + 589824);     //  1638400 B
    unsigned short* qbuf  = (unsigned short*)(ws + 2228224);    // 26214400 B
    unsigned short* kbuf  = (unsigned short*)(ws + 28442624);
    unsigned short* vbuf  = (unsigned short*)(ws + 54657024);
    unsigned short* gbuf  = (unsigned short*)(ws + 80871424);
    unsigned short* wabuf = (unsigned short*)(ws + 107085824);  // ends 133300224
    if (ws_size < 133300224ull) {
        fprintf(stderr, "kernel_launch: ws too small (%zu < 133300224)\n", ws_size);
        return;
    }

    prep_kernel   <<<752,  256, 0, stream>>>(wq, wk, wv, wg, wpb, wo, pmsk, wcat, woutb, maskT);
    ln_proj_kernel<<<1600, 256, 0, stream>>>(act, gam, bet, wcat, qbuf, kbuf, vbuf, gbuf, biasH);
    attn_kernel   <<<6400, 256, 0, stream>>>(qbuf, kbuf, vbuf, gbuf, biasH, maskT, wabuf);
    out_proj_kernel<<<1600, 256, 0, stream>>>(wabuf, woutb, out);
}

// Round 2
// 341.550 us; speedup vs baseline: 1.4617x; 1.4617x over previous
//
#include <hip/hip_runtime.h>
#include <cstdio>
#include <cstdint>

// GridSelfAttention: N=320 seq, C=128 ch, H=4 heads, D=32 head-dim.
// k0 prep -> k1 LN+proj GEMM -> k2 attention -> k3 output GEMM.

#define NSEQ 320
#define CCH  128
#define NN   102400        // NSEQ*NSEQ
#define QK_SCALE 0.17677669529663687f   // 1/sqrt(32), folded into Wq
#define LN_EPS 1e-5f
#define NEG_BIG -1e9f

typedef __bf16 bf16x8 __attribute__((ext_vector_type(8)));
typedef float  f32x4  __attribute__((ext_vector_type(4)));

__device__ __forceinline__ unsigned short f2bf(float f) {
    unsigned int u = __float_as_uint(f);
    unsigned int r = (u + 0x7FFFu + ((u >> 16) & 1u)) >> 16;  // RNE
    return (unsigned short)r;
}
__device__ __forceinline__ float bf2f(unsigned short h) {
    return __uint_as_float(((unsigned int)h) << 16);
}

// ---------------- k0: weight prep ----------------
__global__ __launch_bounds__(256) void prep_kernel(
    const float* __restrict__ wq, const float* __restrict__ wk, const float* __restrict__ wv,
    const float* __restrict__ wg, const float* __restrict__ wpb, const float* __restrict__ wo,
    const int* __restrict__ pmask,
    unsigned short* __restrict__ wcat, unsigned short* __restrict__ woutb, int* __restrict__ maskT)
{
    int idx = blockIdx.x * 256 + threadIdx.x;
    if (idx < 576 * 128) {
        int n = idx >> 7, c = idx & 127;
        float v;
        if      (n < 128) v = wq[c * 128 + n] * QK_SCALE;
        else if (n < 256) v = wk[c * 128 + (n - 128)];
        else if (n < 384) v = wv[c * 128 + (n - 256)];
        else if (n < 512) v = wg[c * 128 + (n - 384)];
        else if (n < 516) v = wpb[c * 4 + (n - 512)];
        else              v = 0.f;
        wcat[idx] = f2bf(v);
    } else if (idx < 576 * 128 + 128 * 128) {
        int i = idx - 576 * 128;
        woutb[i] = f2bf(wo[i]);
    } else if (idx < 576 * 128 + 128 * 128 + NN) {
        int i = idx - (576 * 128 + 128 * 128);
        int b = i / NSEQ, k = i - b * NSEQ;
        maskT[i] = pmask[k * NSEQ + b];
    }
}

// ---------------- k1: LayerNorm + fused projection GEMM ----------------
// biasS is written in MFMA-C-fragment order: [h][q>>4][key>>4][(qm>>2)*64 + kl*4 + (qm&3)]
// so k2 can read its C-operand as one coalesced float4 per lane per tile.
__global__ __launch_bounds__(256, 4) void ln_proj_kernel(
    const float* __restrict__ act, const float* __restrict__ gamma, const float* __restrict__ beta,
    const unsigned short* __restrict__ wcat,
    unsigned short* __restrict__ qb, unsigned short* __restrict__ kb, unsigned short* __restrict__ vb,
    unsigned short* __restrict__ gb, float* __restrict__ biasS)
{
    __shared__ __align__(16) float          fs[64 * 132];            // fp32 act stage, later aliased by B
    __shared__ __align__(16) unsigned short A_lds[64 * 136];
    unsigned short* B_lds = (unsigned short*)fs;                     // alias (33792 B >= 17408 B)

    const int tid  = threadIdx.x;
    const int row0 = blockIdx.x * 64;

    const float4* actv = (const float4*)(act + (size_t)row0 * 128);
    #pragma unroll
    for (int it = 0; it < 8; ++it) {
        int f = it * 256 + tid;
        int row = f >> 5, c4 = f & 31;
        float4 v = actv[f];
        *(float4*)&fs[row * 132 + c4 * 4] = v;
    }
    __syncthreads();

    {
        int row = tid >> 2, seg = tid & 3;
        const float* rp = &fs[row * 132 + seg * 32];
        float vals[32];
        float s = 0.f, sq = 0.f;
        #pragma unroll
        for (int i = 0; i < 32; ++i) { float v = rp[i]; vals[i] = v; s += v; sq += v * v; }
        s  += __shfl_xor(s, 1);  sq += __shfl_xor(sq, 1);
        s  += __shfl_xor(s, 2);  sq += __shfl_xor(sq, 2);
        float mean = s * (1.f / 128.f);
        float var  = sq * (1.f / 128.f) - mean * mean;
        float rstd = rsqrtf(var + LN_EPS);
        #pragma unroll
        for (int j = 0; j < 4; ++j) {
            int c0 = seg * 32 + j * 8;
            float4 g0 = *(const float4*)&gamma[c0];
            float4 g1 = *(const float4*)&gamma[c0 + 4];
            float4 b0 = *(const float4*)&beta[c0];
            float4 b1 = *(const float4*)&beta[c0 + 4];
            union { uint4 u; unsigned short us[8]; } pk;
            pk.us[0] = f2bf((vals[j*8+0] - mean) * rstd * g0.x + b0.x);
            pk.us[1] = f2bf((vals[j*8+1] - mean) * rstd * g0.y + b0.y);
            pk.us[2] = f2bf((vals[j*8+2] - mean) * rstd * g0.z + b0.z);
            pk.us[3] = f2bf((vals[j*8+3] - mean) * rstd * g0.w + b0.w);
            pk.us[4] = f2bf((vals[j*8+4] - mean) * rstd * g1.x + b1.x);
            pk.us[5] = f2bf((vals[j*8+5] - mean) * rstd * g1.y + b1.y);
            pk.us[6] = f2bf((vals[j*8+6] - mean) * rstd * g1.z + b1.z);
            pk.us[7] = f2bf((vals[j*8+7] - mean) * rstd * g1.w + b1.w);
            *(uint4*)&A_lds[row * 136 + c0] = pk.u;
        }
    }
    __syncthreads();

    const int wave = tid >> 6, lane = tid & 63, l15 = lane & 15, l4 = lane >> 4;
    bf16x8 afrag[4];
    #pragma unroll
    for (int kc = 0; kc < 4; ++kc)
        afrag[kc] = *(const bf16x8*)&A_lds[(wave * 16 + l15) * 136 + kc * 32 + l4 * 8];

    for (int nt = 0; nt < 9; ++nt) {
        #pragma unroll
        for (int it = 0; it < 4; ++it) {
            int f = it * 256 + tid;
            int row = f >> 4, c16 = f & 15;
            uint4 u = *(const uint4*)&wcat[(nt * 64 + row) * 128 + c16 * 8];
            *(uint4*)&B_lds[row * 136 + c16 * 8] = u;
        }
        __syncthreads();
        f32x4 acc[4];
        #pragma unroll
        for (int ns = 0; ns < 4; ++ns) { f32x4 z = {0.f,0.f,0.f,0.f}; acc[ns] = z; }
        #pragma unroll
        for (int ns = 0; ns < 4; ++ns)
            #pragma unroll
            for (int kc = 0; kc < 4; ++kc) {
                bf16x8 bfrag = *(const bf16x8*)&B_lds[(ns * 16 + l15) * 136 + kc * 32 + l4 * 8];
                acc[ns] = __builtin_amdgcn_mfma_f32_16x16x32_bf16(afrag[kc], bfrag, acc[ns], 0, 0, 0);
            }
        #pragma unroll
        for (int ns = 0; ns < 4; ++ns) {
            int j = nt * 64 + ns * 16 + l15;
            #pragma unroll
            for (int reg = 0; reg < 4; ++reg) {
                int r = row0 + wave * 16 + l4 * 4 + reg;
                float v = acc[ns][reg];
                if      (j < 128) qb[(size_t)r * 128 + j]         = f2bf(v);
                else if (j < 256) kb[(size_t)r * 128 + (j - 128)] = f2bf(v);
                else if (j < 384) vb[(size_t)r * 128 + (j - 256)] = f2bf(v);
                else if (j < 512) gb[(size_t)r * 128 + (j - 384)] = f2bf(1.f / (1.f + __expf(-v)));
                else if (j < 516) {
                    int hh  = j - 512;
                    int q   = r / 320, key = r - q * 320;
                    int qm  = q & 15,  kl  = key & 15;
                    size_t a = (((size_t)(hh * 20 + (q >> 4)) * 20 + (key >> 4)) << 8)
                             + ((qm >> 2) << 6) + (kl << 2) + (qm & 3);
                    biasS[a] = v;
                }
            }
        }
        __syncthreads();
    }
}

// ---------------- k2: attention ----------------
// block = (b, h, q-tile of 64). 4 waves x 16 q-rows. Q/K frags direct from global.
// V^T via LDS (stride 330: conflict-free). Bias = MFMA C-operand (pre-swizzled float4).
// P streamed to per-wave LDS double-buffer in 32-key chunks (stride 36, conflict-free writes).
__global__ __launch_bounds__(256, 5) void attn_kernel(
    const unsigned short* __restrict__ qb, const unsigned short* __restrict__ kb,
    const unsigned short* __restrict__ vb, const unsigned short* __restrict__ gb,
    const float* __restrict__ biasS, const int* __restrict__ maskT,
    unsigned short* __restrict__ waG)
{
    __shared__ __align__(16) unsigned short Vt[32 * 330];       // 21120 B, V^T [d][key]
    __shared__ __align__(16) unsigned short Pb[4][2][16 * 36];  //  9216 B, per-wave P chunk dbuf

    const int tid  = threadIdx.x;
    const int bid  = blockIdx.x;
    const int b    = bid / 20;
    const int h    = (bid / 5) & 3;
    const int qblk = bid % 5;
    const int wave = tid >> 6, lane = tid & 63, l15 = lane & 15, l4 = lane >> 4;

    // stage V^T: [320 keys x 32 d] -> [32][320] stride 330 (conflict-free writes)
    #pragma unroll
    for (int it = 0; it < 5; ++it) {
        int idx = it * 256 + tid;
        int key = idx >> 2, part = idx & 3;
        union { uint4 u; unsigned short us[8]; } v;
        v.u = *(const uint4*)&vb[(size_t)(b * NSEQ + key) * 128 + h * 32 + part * 8];
        #pragma unroll
        for (int i = 0; i < 8; ++i)
            Vt[(part * 8 + i) * 330 + key] = v.us[i];
    }
    __syncthreads();

    const int qrow = qblk * 64 + wave * 16;
    const int qb16 = qblk * 4 + wave;

    bf16x8 aQ = *(const bf16x8*)&qb[(size_t)(b * NSEQ + qrow + l15) * 128 + h * 32 + l4 * 8];

    // S = Q K^T + bias : bias enters as the MFMA C operand (coalesced float4 per lane)
    const float* bsw = biasS + (size_t)(h * 20 + qb16) * 20 * 256 + lane * 4;
    f32x4 s[20];
    #pragma unroll
    for (int t = 0; t < 20; ++t) {
        f32x4 c = *(const f32x4*)&bsw[t * 256];
        bf16x8 bK = *(const bf16x8*)&kb[(size_t)(b * NSEQ + t * 16 + l15) * 128 + h * 32 + l4 * 8];
        s[t] = __builtin_amdgcn_mfma_f32_16x16x32_bf16(aQ, bK, c, 0, 0, 0);
    }

    // mask (key,b) -> exactly -1e9 (matches reference where-fill)
    const int* mp = maskT + b * NSEQ + l15;
    #pragma unroll
    for (int t = 0; t < 20; ++t) {
        int m = mp[t * 16];
        f32x4 sv = s[t];
        #pragma unroll
        for (int reg = 0; reg < 4; ++reg)
            sv[reg] = m ? sv[reg] : NEG_BIG;
        s[t] = sv;
    }

    // softmax over keys per q-row
    #pragma unroll
    for (int reg = 0; reg < 4; ++reg) {
        float mx = -3.4e38f;
        #pragma unroll
        for (int t = 0; t < 20; ++t) mx = fmaxf(mx, s[t][reg]);
        mx = fmaxf(mx, __shfl_xor(mx, 1));
        mx = fmaxf(mx, __shfl_xor(mx, 2));
        mx = fmaxf(mx, __shfl_xor(mx, 4));
        mx = fmaxf(mx, __shfl_xor(mx, 8));
        float l = 0.f;
        #pragma unroll
        for (int t = 0; t < 20; ++t) { float p = __expf(s[t][reg] - mx); s[t][reg] = p; l += p; }
        l += __shfl_xor(l, 1); l += __shfl_xor(l, 2); l += __shfl_xor(l, 4); l += __shfl_xor(l, 8);
        float wv = 1.f / l;   // fully-masked row -> uniform 1/320, matches reference
        #pragma unroll
        for (int t = 0; t < 20; ++t) s[t][reg] *= wv;
    }

    // PV with P streamed through per-wave LDS chunk double-buffer (32 keys/chunk).
    // Same-wave LDS ordering is in-order; no barriers needed.
    unsigned short* pb[2] = { Pb[wave][0], Pb[wave][1] };
    #pragma unroll
    for (int tt = 0; tt < 2; ++tt)
        #pragma unroll
        for (int reg = 0; reg < 4; ++reg)
            pb[0][(l4 * 4 + reg) * 36 + tt * 16 + l15] = f2bf(s[tt][reg]);

    f32x4 acc[2];
    { f32x4 z = {0.f,0.f,0.f,0.f}; acc[0] = z; acc[1] = z; }
    #pragma unroll
    for (int kc = 0; kc < 10; ++kc) {
        bf16x8 aW = *(const bf16x8*)&pb[kc & 1][l15 * 36 + l4 * 8];
        if (kc < 9) {
            unsigned short* nxt = pb[(kc + 1) & 1];
            #pragma unroll
            for (int tt = 0; tt < 2; ++tt)
                #pragma unroll
                for (int reg = 0; reg < 4; ++reg)
                    nxt[(l4 * 4 + reg) * 36 + tt * 16 + l15] = f2bf(s[2 * kc + 2 + tt][reg]);
        }
        #pragma unroll
        for (int ns = 0; ns < 2; ++ns) {
            bf16x8 bV = *(const bf16x8*)&Vt[(ns * 16 + l15) * 330 + kc * 32 + l4 * 8];
            acc[ns] = __builtin_amdgcn_mfma_f32_16x16x32_bf16(aW, bV, acc[ns], 0, 0, 0);
        }
    }

    // epilogue: wa * gate -> bf16
    #pragma unroll
    for (int ns = 0; ns < 2; ++ns)
        #pragma unroll
        for (int reg = 0; reg < 4; ++reg) {
            int r   = b * NSEQ + qrow + l4 * 4 + reg;
            int col = h * 32 + ns * 16 + l15;
            float g = bf2f(gb[(size_t)r * 128 + col]);
            waG[(size_t)r * 128 + col] = f2bf(acc[ns][reg] * g);
        }
}

// ---------------- k3: output projection ----------------
__global__ __launch_bounds__(256, 4) void out_proj_kernel(
    const unsigned short* __restrict__ waG, const unsigned short* __restrict__ woutb,
    float* __restrict__ out)
{
    __shared__ __align__(16) unsigned short A_lds[64 * 136];
    __shared__ __align__(16) unsigned short B_lds[128 * 136];
    const int tid  = threadIdx.x;
    const int row0 = blockIdx.x * 64;

    #pragma unroll
    for (int it = 0; it < 4; ++it) {
        int f = it * 256 + tid;
        int row = f >> 4, c16 = f & 15;
        uint4 u = *(const uint4*)&waG[(size_t)(row0 + row) * 128 + c16 * 8];
        *(uint4*)&A_lds[row * 136 + c16 * 8] = u;
    }
    #pragma unroll
    for (int it = 0; it < 8; ++it) {
        int f = it * 256 + tid;
        int row = f >> 4, c16 = f & 15;
        uint4 u = *(const uint4*)&woutb[f * 8];
        *(uint4*)&B_lds[row * 136 + c16 * 8] = u;
    }
    __syncthreads();

    const int wave = tid >> 6, lane = tid & 63, l15 = lane & 15, l4 = lane >> 4;
    bf16x8 afrag[4];
    #pragma unroll
    for (int kc = 0; kc < 4; ++kc)
        afrag[kc] = *(const bf16x8*)&A_lds[(wave * 16 + l15) * 136 + kc * 32 + l4 * 8];
    f32x4 acc[8];
    #pragma unroll
    for (int ns = 0; ns < 8; ++ns) { f32x4 z = {0.f,0.f,0.f,0.f}; acc[ns] = z; }
    #pragma unroll
    for (int ns = 0; ns < 8; ++ns)
        #pragma unroll
        for (int kc = 0; kc < 4; ++kc) {
            bf16x8 bfrag = *(const bf16x8*)&B_lds[(ns * 16 + l15) * 136 + kc * 32 + l4 * 8];
            acc[ns] = __builtin_amdgcn_mfma_f32_16x16x32_bf16(afrag[kc], bfrag, acc[ns], 0, 0, 0);
        }
    #pragma unroll
    for (int ns = 0; ns < 8; ++ns)
        #pragma unroll
        for (int reg = 0; reg < 4; ++reg) {
            int r = row0 + wave * 16 + l4 * 4 + reg;
            out[(size_t)r * 128 + ns * 16 + l15] = acc[ns][reg];
        }
}

// ---------------- launch ----------------
extern "C" void kernel_launch(void* const* d_in, const int* in_sizes, int n_in,
                              void* d_out, int out_size, void* d_ws, size_t ws_size,
                              hipStream_t stream)
{
    (void)in_sizes; (void)n_in; (void)out_size;
    const float* act  = (const float*)d_in[0];
    const int*   pmsk = (const int*)d_in[1];
    const float* gam  = (const float*)d_in[2];
    const float* bet  = (const float*)d_in[3];
    const float* wpb  = (const float*)d_in[4];
    const float* wq   = (const float*)d_in[5];
    const float* wk   = (const float*)d_in[6];
    const float* wv   = (const float*)d_in[7];
    const float* wg   = (const float*)d_in[8];
    const float* wo   = (const float*)d_in[9];
    float* out = (float*)d_out;

    char* ws = (char*)d_ws;
    unsigned short* wcat  = (unsigned short*)(ws + 0);          //   147456 B
    unsigned short* woutb = (unsigned short*)(ws + 147456);     //    32768 B
    int*            maskT = (int*)           (ws + 180224);     //   409600 B
    float*          biasS = (float*)         (ws + 589824);     //  1638400 B (swizzled)
    unsigned short* qbuf  = (unsigned short*)(ws + 2228224);    // 26214400 B
    unsigned short* kbuf  = (unsigned short*)(ws + 28442624);
    unsigned short* vbuf  = (unsigned short*)(ws + 54657024);
    unsigned short* gbuf  = (unsigned short*)(ws + 80871424);
    unsigned short* wabuf = (unsigned short*)(ws + 107085824);  // ends 133300224
    if (ws_size < 133300224ull) {
        fprintf(stderr, "kernel_launch: ws too small (%zu < 133300224)\n", ws_size);
        return;
    }

    prep_kernel    <<<752,  256, 0, stream>>>(wq, wk, wv, wg, wpb, wo, pmsk, wcat, woutb, maskT);
    ln_proj_kernel <<<1600, 256, 0, stream>>>(act, gam, bet, wcat, qbuf, kbuf, vbuf, gbuf, biasS);
    attn_kernel    <<<6400, 256, 0, stream>>>(qbuf, kbuf, vbuf, gbuf, biasS, maskT, wabuf);
    out_proj_kernel<<<1600, 256, 0, stream>>>(wabuf, woutb, out);
}